// Round 13
// baseline (300.748 us; speedup 1.0000x reference)
//
#include <hip/hip_runtime.h>

#define N_NODES 100000
#define N_EDGES 1600000
#define N_GRAPHS 512
#define NBUCK 782          // buckets of 128 nodes (ceil(100000/128))
#define EPB 2048           // edges per block for scatter (782 blocks ~ 3/CU)
#define NB_SCAT ((N_EDGES + EPB - 1) / EPB)   // 782
#define CAPB 2688          // slot capacity per bucket (mean 2046, +14 sigma)
#define CONV_BLKS 6250     // N_NODES*16/256

typedef _Float16 half8 __attribute__((ext_vector_type(8)));
typedef float floatx4 __attribute__((ext_vector_type(4)));

union U16 { uint4 u; half8 h; };

// ---------- merged convert + pack_w + gcur zero ----------
__global__ __launch_bounds__(256) void convert_pack(const float4* __restrict__ X4,
                                                    uint4* __restrict__ Xh,
                                                    const float* __restrict__ W0,
                                                    const float* __restrict__ W1,
                                                    const float* __restrict__ W2,
                                                    uint4* __restrict__ Bp,
                                                    int* __restrict__ gcur) {
    int bid = blockIdx.x, tid = threadIdx.x;
    if (bid < CONV_BLKS) {
        int t = bid * 256 + tid;
        float4 a = X4[t * 2], b = X4[t * 2 + 1];
        U16 o;
        o.h[0] = (_Float16)a.x; o.h[1] = (_Float16)a.y;
        o.h[2] = (_Float16)a.z; o.h[3] = (_Float16)a.w;
        o.h[4] = (_Float16)b.x; o.h[5] = (_Float16)b.y;
        o.h[6] = (_Float16)b.z; o.h[7] = (_Float16)b.w;
        Xh[t] = o.u;
    } else {
        int zi = (bid - CONV_BLKS) * 256 + tid;
        if (zi < NBUCK) gcur[zi] = 0;
        // Bp[layer*2048 + (c*8+f)*64 + l] = W[(f*16+(l&15))*128 + c*32 + (l>>4)*8 + j]
        int slice = (bid - CONV_BLKS) * 4 + (tid >> 6);   // 0..95
        if (slice >= 96) return;
        int l = tid & 63;
        int layer = slice >> 5;
        int r = slice & 31;
        int c = r >> 3, f = r & 7;
        const float* W = (layer == 0) ? W0 : (layer == 1) ? W1 : W2;
        int col = f * 16 + (l & 15);
        int k0 = c * 32 + (l >> 4) * 8;
        U16 o;
        #pragma unroll
        for (int j = 0; j < 8; ++j) o.h[j] = (_Float16)W[col * 128 + k0 + j];
        Bp[layer * 2048 + (c * 8 + f) * 64 + l] = o.u;
    }
}

// ---------- bucket scatter: pairs entry = src | (dst&127)<<17 ----------
__global__ __launch_bounds__(256) void bucket_scatter(const int* __restrict__ src,
                                                      const int* __restrict__ dst,
                                                      int* __restrict__ gcur,
                                                      unsigned* __restrict__ pairs) {
    __shared__ int cnt[NBUCK];
    __shared__ int base[NBUCK];
    int tid = threadIdx.x;
    for (int i = tid; i < NBUCK; i += 256) cnt[i] = 0;
    __syncthreads();
    int e0 = blockIdx.x * EPB, e1 = min(e0 + EPB, N_EDGES);
    for (int e = e0 + tid; e < e1; e += 256) atomicAdd(&cnt[dst[e] >> 7], 1);
    __syncthreads();
    for (int i = tid; i < NBUCK; i += 256) {
        int v = cnt[i];
        base[i] = i * CAPB + (v ? atomicAdd(&gcur[i], v) : 0);
        cnt[i] = 0;
    }
    __syncthreads();
    for (int e = e0 + tid; e < e1; e += 256) {
        int d = dst[e], b = d >> 7;
        int r = atomicAdd(&cnt[b], 1);
        pairs[base[b] + r] = (unsigned)src[e] | ((unsigned)(d & 127) << 17);
    }
}

// ---------- fine sort within 128-node bucket (inline global prefix) ----------
__global__ __launch_bounds__(256) void bucket_fine(const unsigned* __restrict__ pairs,
                                                   const int* __restrict__ gcur,
                                                   int* __restrict__ off,
                                                   int* __restrict__ srclist) {
    __shared__ int snap[NBUCK];     // bucket counts -> exclusive prefix
    __shared__ int ncnt[128];
    __shared__ int ws[2];
    int tid = threadIdx.x, b = blockIdx.x;

    for (int i = tid; i < NBUCK; i += 256) snap[i] = gcur[i];
    if (tid < 128) ncnt[tid] = 0;
    __syncthreads();
    // wave 0: exclusive prefix over snap[0..NBUCK)
    if (tid < 64) {
        int carry = 0;
        #pragma unroll 1
        for (int base = 0; base < NBUCK; base += 64) {
            int i = base + tid;
            int v = (i < NBUCK) ? snap[i] : 0;
            int incl = v;
            #pragma unroll
            for (int s = 1; s < 64; s <<= 1) {
                int y = __shfl_up(incl, s, 64);
                if (tid >= s) incl += y;
            }
            if (i < NBUCK) snap[i] = carry + incl - v;
            carry += __shfl(incl, 63, 64);
        }
    }
    __syncthreads();
    int eLo = snap[b];
    int eNext = (b == NBUCK - 1) ? N_EDGES : snap[b + 1];
    int m = eNext - eLo;
    int sb = b * CAPB;
    if (b == 0 && tid == 0) off[N_NODES] = N_EDGES;
    __syncthreads();

    for (int t = tid; t < m; t += 256) {
        unsigned p = pairs[sb + t];
        atomicAdd(&ncnt[(p >> 17) & 127], 1);
    }
    __syncthreads();
    int v = 0, incl = 0;
    if (tid < 128) {
        v = ncnt[tid];
        incl = v;
        int lane = tid & 63;
        #pragma unroll
        for (int s = 1; s < 64; s <<= 1) {
            int y = __shfl_up(incl, s, 64);
            if (lane >= s) incl += y;
        }
        if (lane == 63) ws[tid >> 6] = incl;
    }
    __syncthreads();
    if (tid < 128) {
        int excl = (tid >= 64 ? ws[0] : 0) + incl - v;
        int n = (b << 7) + tid;
        if (n < N_NODES) off[n] = eLo + excl;
        ncnt[tid] = excl;   // cursor
    }
    __syncthreads();
    // direct scatter: writes stay within this bucket's ~8 KB srclist window
    for (int t = tid; t < m; t += 256) {
        unsigned p = pairs[sb + t];
        int r = atomicAdd(&ncnt[(p >> 17) & 127], 1);
        srclist[eLo + r] = (int)(p & 0x1FFFFu);
    }
}

// ---------- fused GIN layer, 2-batch pipelined: 32 nodes/block, grid 3125 ----------
__device__ __forceinline__ half8 gather_row(const uint4* __restrict__ Xh,
                                            const int* __restrict__ off,
                                            const int* __restrict__ srclist,
                                            int n, int c) {
    int j0 = off[n], j1 = off[n + 1];
    U16 acc; acc.u = Xh[(size_t)n * 16 + c];   // own row (GIN eps=0)
    half8 a = acc.h;
    int j = j0;
    for (; j + 3 < j1; j += 4) {
        int s0 = srclist[j], s1 = srclist[j + 1], s2 = srclist[j + 2], s3 = srclist[j + 3];
        U16 v0, v1, v2, v3;
        v0.u = Xh[(size_t)s0 * 16 + c];
        v1.u = Xh[(size_t)s1 * 16 + c];
        v2.u = Xh[(size_t)s2 * 16 + c];
        v3.u = Xh[(size_t)s3 * 16 + c];
        a += v0.h; a += v1.h; a += v2.h; a += v3.h;
    }
    for (; j < j1; ++j) {
        U16 v; v.u = Xh[(size_t)srclist[j] * 16 + c];
        a += v.h;
    }
    return a;
}

__device__ __forceinline__ void mfma_store(const ushort* __restrict__ buf,
                                           const uint4* __restrict__ Bp,
                                           const float* __restrict__ bias,
                                           _Float16* __restrict__ H,
                                           int nodebase, int wid, int lane, int doRelu) {
    int lrow = lane & 15;
    int lk8 = (lane >> 4) * 8;
    floatx4 acc2[2];
    acc2[0] = (floatx4)0.f;
    acc2[1] = (floatx4)0.f;
    #pragma unroll
    for (int c4 = 0; c4 < 4; ++c4) {
        U16 af; af.u = *(const uint4*)&buf[lrow * 136 + c4 * 32 + lk8];
        #pragma unroll
        for (int q = 0; q < 2; ++q) {
            int f = wid * 2 + q;
            U16 b; b.u = Bp[(c4 * 8 + f) * 64 + lane];
            // swapped: W-frag as A operand -> D col = node, D row = feature
            acc2[q] = __builtin_amdgcn_mfma_f32_16x16x32_f16(b.h, af.h, acc2[q], 0, 0, 0);
        }
    }
    int ncol = lane & 15;
    int rq = (lane >> 4) * 4;
    int node = nodebase + ncol;
    #pragma unroll
    for (int q = 0; q < 2; ++q) {
        int f = wid * 2 + q;
        float4 bv = *(const float4*)(bias + f * 16 + rq);
        float o0 = acc2[q][0] + bv.x;
        float o1 = acc2[q][1] + bv.y;
        float o2 = acc2[q][2] + bv.z;
        float o3 = acc2[q][3] + bv.w;
        if (doRelu) {
            o0 = fmaxf(o0, 0.f); o1 = fmaxf(o1, 0.f);
            o2 = fmaxf(o2, 0.f); o3 = fmaxf(o3, 0.f);
        }
        ushort4 st;
        st.x = (unsigned short)__builtin_bit_cast(unsigned short, (_Float16)o0);
        st.y = (unsigned short)__builtin_bit_cast(unsigned short, (_Float16)o1);
        st.z = (unsigned short)__builtin_bit_cast(unsigned short, (_Float16)o2);
        st.w = (unsigned short)__builtin_bit_cast(unsigned short, (_Float16)o3);
        *(ushort4*)(H + (size_t)node * 128 + f * 16 + rq) = st;
    }
}

__global__ __launch_bounds__(256) void gin_fused(const uint4* __restrict__ Xh,
                                                 const uint4* __restrict__ Bp,
                                                 const float* __restrict__ bias,
                                                 _Float16* __restrict__ H,
                                                 const int* __restrict__ off,
                                                 const int* __restrict__ srclist,
                                                 int doRelu) {
    __shared__ ushort lds[2][16 * 136];
    int tid = threadIdx.x;
    int n0 = blockIdx.x * 32;          // 3125*32 == N_NODES exactly
    int r = tid >> 4, c = tid & 15;
    int wid = tid >> 6, lane = tid & 63;

    // gather batch 0 -> lds[0]
    {
        half8 a = gather_row(Xh, off, srclist, n0 + r, c);
        U16 o; o.h = a;
        *(uint4*)&lds[0][r * 136 + c * 8] = o.u;
    }
    __syncthreads();
    // MFMA batch 0 (lds[0]) then gather batch 1 -> lds[1] (no barrier needed between:
    // nobody rewrites lds[0]; lds[1] writes are fenced by the next barrier)
    mfma_store(lds[0], Bp, bias, H, n0, wid, lane, doRelu);
    {
        half8 a = gather_row(Xh, off, srclist, n0 + 16 + r, c);
        U16 o; o.h = a;
        *(uint4*)&lds[1][r * 136 + c * 8] = o.u;
    }
    __syncthreads();
    mfma_store(lds[1], Bp, bias, H, n0 + 16, wid, lane, doRelu);
}

// ---------- pooling + classifier ----------
__device__ __forceinline__ int lower_bound_i(const int* a, int n, int val) {
    int lo = 0, hi = n;
    while (lo < hi) {
        int mid = (lo + hi) >> 1;
        if (a[mid] < val) lo = mid + 1; else hi = mid;
    }
    return lo;
}

__global__ __launch_bounds__(256) void pool_kernel(const uint4* __restrict__ Hh,
                                                   const int* __restrict__ batch,
                                                   const float* __restrict__ Wg,
                                                   const float* __restrict__ bg,
                                                   float* __restrict__ out) {
    __shared__ float p[16 * 128];
    __shared__ float pooled[128];
    int g = blockIdx.x, tid = threadIdx.x;
    int c = tid & 15, r = tid >> 4;
    int lo = lower_bound_i(batch, N_NODES, g);
    int hi = lower_bound_i(batch, N_NODES, g + 1);
    float acc[8] = {0, 0, 0, 0, 0, 0, 0, 0};
    for (int i = lo + r; i < hi; i += 16) {
        U16 v; v.u = Hh[(size_t)i * 16 + c];
        #pragma unroll
        for (int k = 0; k < 8; ++k) acc[k] += (float)v.h[k];
    }
    #pragma unroll
    for (int k = 0; k < 8; ++k) p[r * 128 + c * 8 + k] = acc[k];
    __syncthreads();
    if (tid < 128) {
        float s = 0.f;
        #pragma unroll
        for (int q = 0; q < 16; ++q) s += p[q * 128 + tid];
        pooled[tid] = s / fmaxf((float)(hi - lo), 1.0f);
    }
    __syncthreads();
    if (tid < 10) {
        float s = bg[tid];
        #pragma unroll 4
        for (int k = 0; k < 128; ++k) s += pooled[k] * Wg[tid * 128 + k];
        out[g * 10 + tid] = s;
    }
}

// ---------- launch ----------
extern "C" void kernel_launch(void* const* d_in, const int* in_sizes, int n_in,
                              void* d_out, int out_size, void* d_ws, size_t ws_size,
                              hipStream_t stream) {
    const float* x   = (const float*)d_in[0];
    const int*   ei  = (const int*)d_in[1];
    const int*   bat = (const int*)d_in[2];
    const float* W0  = (const float*)d_in[3];
    const float* b0  = (const float*)d_in[4];
    const float* W1  = (const float*)d_in[5];
    const float* b1  = (const float*)d_in[6];
    const float* W2  = (const float*)d_in[7];
    const float* b2  = (const float*)d_in[8];
    const float* Wg  = (const float*)d_in[9];
    const float* bg  = (const float*)d_in[10];
    float* out = (float*)d_out;

    const int* src = ei;
    const int* dst = ei + N_EDGES;

    char* w = (char*)d_ws;
    unsigned* pairs = (unsigned*)(w);               // 8.4 MB (CSR staging only)
    _Float16* P0    = (_Float16*)(w + 25600000);    // X mirror; later H2
    _Float16* P1    = (_Float16*)(w + 51200000);    // H0
    _Float16* P2    = (_Float16*)(w + 76800000);    // H1
    int*    srclist = (int*)(w + 102400000);        // 6.4 MB
    int*    off     = (int*)(w + 108800000);        // 400,016 B
    uint4*  Bp      = (uint4*)(w + 109300000);      // 98,304 B
    int*    gcur    = (int*)(w + 109450000);        // NBUCK ints

    // convert + pack + gcur zero (must precede scatter)
    convert_pack<<<CONV_BLKS + 24, 256, 0, stream>>>((const float4*)x, (uint4*)P0,
                                                     W0, W1, W2, Bp, gcur);
    // CSR build
    bucket_scatter<<<NB_SCAT, 256, 0, stream>>>(src, dst, gcur, pairs);
    bucket_fine<<<NBUCK, 256, 0, stream>>>(pairs, gcur, off, srclist);

    int grid = N_NODES / 32;   // 3125

    // layer 0: P0 -> P1
    gin_fused<<<grid, 256, 0, stream>>>((const uint4*)P0, Bp, b0, P1, off, srclist, 1);
    // layer 1: P1 -> P2
    gin_fused<<<grid, 256, 0, stream>>>((const uint4*)P1, Bp + 2048, b1, P2, off, srclist, 1);
    // layer 2: P2 -> P0
    gin_fused<<<grid, 256, 0, stream>>>((const uint4*)P2, Bp + 4096, b2, P0, off, srclist, 0);

    // pool + classifier
    pool_kernel<<<N_GRAPHS, 256, 0, stream>>>((const uint4*)P0, bat, Wg, bg, out);
}

// Round 14
// 281.995 us; speedup vs baseline: 1.0665x; 1.0665x over previous
//
#include <hip/hip_runtime.h>

#define N_NODES 100000
#define N_EDGES 1600000
#define N_GRAPHS 512
#define NBUCK 391          // ceil(N_NODES / 256)
#define EPB 2048           // edges per block for scatter (782 blocks ~ 3/CU)
#define NB_SCAT ((N_EDGES + EPB - 1) / EPB)   // 782
#define CAPB 4864          // slot capacity per bucket (mean 4092, +12 sigma)
#define CONV_BLKS 6250     // N_NODES*16/256

typedef _Float16 half8 __attribute__((ext_vector_type(8)));
typedef float floatx4 __attribute__((ext_vector_type(4)));

union U16 { uint4 u; half8 h; };

// ---------- merged convert + pack_w + gcur zero ----------
__global__ __launch_bounds__(256) void convert_pack(const float4* __restrict__ X4,
                                                    uint4* __restrict__ Xh,
                                                    const float* __restrict__ W0,
                                                    const float* __restrict__ W1,
                                                    const float* __restrict__ W2,
                                                    uint4* __restrict__ Bp,
                                                    int* __restrict__ gcur) {
    int bid = blockIdx.x, tid = threadIdx.x;
    if (bid < CONV_BLKS) {
        int t = bid * 256 + tid;
        float4 a = X4[t * 2], b = X4[t * 2 + 1];
        U16 o;
        o.h[0] = (_Float16)a.x; o.h[1] = (_Float16)a.y;
        o.h[2] = (_Float16)a.z; o.h[3] = (_Float16)a.w;
        o.h[4] = (_Float16)b.x; o.h[5] = (_Float16)b.y;
        o.h[6] = (_Float16)b.z; o.h[7] = (_Float16)b.w;
        Xh[t] = o.u;
    } else {
        int zi = (bid - CONV_BLKS) * 256 + tid;
        if (zi < NBUCK) gcur[zi] = 0;
        // Bp[layer*2048 + (c*8+f)*64 + l] = W[(f*16+(l&15))*128 + c*32 + (l>>4)*8 + j]
        int slice = (bid - CONV_BLKS) * 4 + (tid >> 6);   // 0..95
        if (slice >= 96) return;
        int l = tid & 63;
        int layer = slice >> 5;
        int r = slice & 31;
        int c = r >> 3, f = r & 7;
        const float* W = (layer == 0) ? W0 : (layer == 1) ? W1 : W2;
        int col = f * 16 + (l & 15);
        int k0 = c * 32 + (l >> 4) * 8;
        U16 o;
        #pragma unroll
        for (int j = 0; j < 8; ++j) o.h[j] = (_Float16)W[col * 128 + k0 + j];
        Bp[layer * 2048 + (c * 8 + f) * 64 + l] = o.u;
    }
}

// ---------- bucket scatter: pairs entry = src | (dst&255)<<17 ----------
__global__ __launch_bounds__(256) void bucket_scatter(const int* __restrict__ src,
                                                      const int* __restrict__ dst,
                                                      int* __restrict__ gcur,
                                                      unsigned* __restrict__ pairs) {
    __shared__ int cnt[NBUCK];
    __shared__ int base[NBUCK];
    int tid = threadIdx.x;
    for (int i = tid; i < NBUCK; i += 256) cnt[i] = 0;
    __syncthreads();
    int e0 = blockIdx.x * EPB, e1 = min(e0 + EPB, N_EDGES);
    for (int e = e0 + tid; e < e1; e += 256) atomicAdd(&cnt[dst[e] >> 8], 1);
    __syncthreads();
    for (int i = tid; i < NBUCK; i += 256) {
        int v = cnt[i];
        base[i] = i * CAPB + (v ? atomicAdd(&gcur[i], v) : 0);
        cnt[i] = 0;
    }
    __syncthreads();
    for (int e = e0 + tid; e < e1; e += 256) {
        int d = dst[e], b = d >> 8;
        int r = atomicAdd(&cnt[b], 1);
        pairs[base[b] + r] = (unsigned)src[e] | ((unsigned)(d & 255) << 17);
    }
}

// ---------- fine sort within bucket (inline global prefix) -> off[] + srclist[] ----------
__global__ __launch_bounds__(256) void bucket_fine(const unsigned* __restrict__ pairs,
                                                   const int* __restrict__ gcur,
                                                   int* __restrict__ off,
                                                   int* __restrict__ srclist) {
    __shared__ int snap[NBUCK];     // bucket counts -> exclusive prefix
    __shared__ int ncnt[256];
    __shared__ int ws[4];
    int tid = threadIdx.x, b = blockIdx.x;
    int lane = tid & 63, w = tid >> 6;

    for (int i = tid; i < NBUCK; i += 256) snap[i] = gcur[i];
    ncnt[tid] = 0;
    __syncthreads();
    if (tid < 64) {
        int carry = 0;
        for (int base = 0; base < NBUCK; base += 64) {
            int i = base + tid;
            int v = (i < NBUCK) ? snap[i] : 0;
            int incl = v;
            #pragma unroll
            for (int s = 1; s < 64; s <<= 1) {
                int y = __shfl_up(incl, s, 64);
                if (tid >= s) incl += y;
            }
            if (i < NBUCK) snap[i] = carry + incl - v;
            carry += __shfl(incl, 63, 64);
        }
    }
    __syncthreads();
    int eLo = snap[b];
    int eNext = (b == NBUCK - 1) ? N_EDGES : snap[b + 1];
    int m = eNext - eLo;
    int sb = b * CAPB;
    if (b == 0 && tid == 0) off[N_NODES] = N_EDGES;
    __syncthreads();

    for (int t = tid; t < m; t += 256) {
        unsigned p = pairs[sb + t];
        atomicAdd(&ncnt[(p >> 17) & 255], 1);
    }
    __syncthreads();
    int v = ncnt[tid];
    int incl = v;
    #pragma unroll
    for (int s = 1; s < 64; s <<= 1) { int y = __shfl_up(incl, s, 64); if (lane >= s) incl += y; }
    if (lane == 63) ws[w] = incl;
    __syncthreads();
    if (tid < 4) {
        int t = ws[tid];
        #pragma unroll
        for (int s = 1; s < 4; s <<= 1) { int y = __shfl_up(t, s, 64); if (tid >= s) t += y; }
        ws[tid] = t;
    }
    __syncthreads();
    int excl = (w ? ws[w - 1] : 0) + incl - v;
    int n = (b << 8) + tid;
    if (n < N_NODES) off[n] = eLo + excl;
    __syncthreads();
    ncnt[tid] = excl;   // cursor
    __syncthreads();
    for (int t = tid; t < m; t += 256) {
        unsigned p = pairs[sb + t];
        int r = atomicAdd(&ncnt[(p >> 17) & 255], 1);
        srclist[eLo + r] = (int)(p & 0x1FFFFu);
    }
}

// ---------- fused GIN layer at agg granularity: 16 nodes/block, grid 6250 ----------
// Phase 1 = r3 agg structure (unroll-4, 16 lanes/node) -> LDS (4.25 KB).
// Phase 2 = swapped-operand MFMA: wave w computes f-frags {2w,2w+1}.
__global__ __launch_bounds__(256) void gin_fused(const uint4* __restrict__ Xh,
                                                 const uint4* __restrict__ Bp,
                                                 const float* __restrict__ bias,
                                                 _Float16* __restrict__ H,
                                                 const int* __restrict__ off,
                                                 const int* __restrict__ srclist,
                                                 int doRelu) {
    __shared__ ushort lds[16 * 136];
    int tid = threadIdx.x;
    int n0 = blockIdx.x * 16;
    int r = tid >> 4;          // local row 0..15
    int c = tid & 15;          // 16B chunk
    int n = n0 + r;            // 6250*16 == N_NODES exactly

    int j0 = off[n], j1 = off[n + 1];
    U16 acc; acc.u = Xh[(size_t)n * 16 + c];   // own row (GIN eps=0)
    half8 a = acc.h;
    int j = j0;
    for (; j + 3 < j1; j += 4) {
        int s0 = srclist[j], s1 = srclist[j + 1], s2 = srclist[j + 2], s3 = srclist[j + 3];
        U16 v0, v1, v2, v3;
        v0.u = Xh[(size_t)s0 * 16 + c];
        v1.u = Xh[(size_t)s1 * 16 + c];
        v2.u = Xh[(size_t)s2 * 16 + c];
        v3.u = Xh[(size_t)s3 * 16 + c];
        a += v0.h; a += v1.h; a += v2.h; a += v3.h;
    }
    for (; j < j1; ++j) {
        U16 v; v.u = Xh[(size_t)srclist[j] * 16 + c];
        a += v.h;
    }
    U16 o; o.h = a;
    *(uint4*)&lds[r * 136 + c * 8] = o.u;
    __syncthreads();

    // phase 2: MFMA from LDS
    int wid = tid >> 6, lane = tid & 63;
    int lrow = lane & 15;
    int lk8 = (lane >> 4) * 8;

    floatx4 acc2[2];
    acc2[0] = (floatx4)0.f;
    acc2[1] = (floatx4)0.f;
    #pragma unroll
    for (int c4 = 0; c4 < 4; ++c4) {
        U16 af; af.u = *(const uint4*)&lds[lrow * 136 + c4 * 32 + lk8];
        #pragma unroll
        for (int q = 0; q < 2; ++q) {
            int f = wid * 2 + q;
            U16 b; b.u = Bp[(c4 * 8 + f) * 64 + lane];
            // swapped: W-frag as A operand -> D col = node, D row = feature
            acc2[q] = __builtin_amdgcn_mfma_f32_16x16x32_f16(b.h, af.h, acc2[q], 0, 0, 0);
        }
    }

    int ncol = lane & 15;
    int rq = (lane >> 4) * 4;
    int node = n0 + ncol;
    #pragma unroll
    for (int q = 0; q < 2; ++q) {
        int f = wid * 2 + q;
        float4 bv = *(const float4*)(bias + f * 16 + rq);
        float o0 = acc2[q][0] + bv.x;
        float o1 = acc2[q][1] + bv.y;
        float o2 = acc2[q][2] + bv.z;
        float o3 = acc2[q][3] + bv.w;
        if (doRelu) {
            o0 = fmaxf(o0, 0.f); o1 = fmaxf(o1, 0.f);
            o2 = fmaxf(o2, 0.f); o3 = fmaxf(o3, 0.f);
        }
        ushort4 st;
        st.x = (unsigned short)__builtin_bit_cast(unsigned short, (_Float16)o0);
        st.y = (unsigned short)__builtin_bit_cast(unsigned short, (_Float16)o1);
        st.z = (unsigned short)__builtin_bit_cast(unsigned short, (_Float16)o2);
        st.w = (unsigned short)__builtin_bit_cast(unsigned short, (_Float16)o3);
        *(ushort4*)(H + (size_t)node * 128 + f * 16 + rq) = st;
    }
}

// ---------- pooling + classifier ----------
__device__ __forceinline__ int lower_bound_i(const int* a, int n, int val) {
    int lo = 0, hi = n;
    while (lo < hi) {
        int mid = (lo + hi) >> 1;
        if (a[mid] < val) lo = mid + 1; else hi = mid;
    }
    return lo;
}

__global__ __launch_bounds__(256) void pool_kernel(const uint4* __restrict__ Hh,
                                                   const int* __restrict__ batch,
                                                   const float* __restrict__ Wg,
                                                   const float* __restrict__ bg,
                                                   float* __restrict__ out) {
    __shared__ float p[16 * 128];
    __shared__ float pooled[128];
    int g = blockIdx.x, tid = threadIdx.x;
    int c = tid & 15, r = tid >> 4;
    int lo = lower_bound_i(batch, N_NODES, g);
    int hi = lower_bound_i(batch, N_NODES, g + 1);
    float acc[8] = {0, 0, 0, 0, 0, 0, 0, 0};
    for (int i = lo + r; i < hi; i += 16) {
        U16 v; v.u = Hh[(size_t)i * 16 + c];
        #pragma unroll
        for (int k = 0; k < 8; ++k) acc[k] += (float)v.h[k];
    }
    #pragma unroll
    for (int k = 0; k < 8; ++k) p[r * 128 + c * 8 + k] = acc[k];
    __syncthreads();
    if (tid < 128) {
        float s = 0.f;
        #pragma unroll
        for (int q = 0; q < 16; ++q) s += p[q * 128 + tid];
        pooled[tid] = s / fmaxf((float)(hi - lo), 1.0f);
    }
    __syncthreads();
    if (tid < 10) {
        float s = bg[tid];
        #pragma unroll 4
        for (int k = 0; k < 128; ++k) s += pooled[k] * Wg[tid * 128 + k];
        out[g * 10 + tid] = s;
    }
}

// ---------- launch ----------
extern "C" void kernel_launch(void* const* d_in, const int* in_sizes, int n_in,
                              void* d_out, int out_size, void* d_ws, size_t ws_size,
                              hipStream_t stream) {
    const float* x   = (const float*)d_in[0];
    const int*   ei  = (const int*)d_in[1];
    const int*   bat = (const int*)d_in[2];
    const float* W0  = (const float*)d_in[3];
    const float* b0  = (const float*)d_in[4];
    const float* W1  = (const float*)d_in[5];
    const float* b1  = (const float*)d_in[6];
    const float* W2  = (const float*)d_in[7];
    const float* b2  = (const float*)d_in[8];
    const float* Wg  = (const float*)d_in[9];
    const float* bg  = (const float*)d_in[10];
    float* out = (float*)d_out;

    const int* src = ei;
    const int* dst = ei + N_EDGES;

    char* w = (char*)d_ws;
    unsigned* pairs = (unsigned*)(w);               // 7.6 MB (CSR staging only)
    _Float16* P0    = (_Float16*)(w + 25600000);    // X mirror; later H2
    _Float16* P1    = (_Float16*)(w + 51200000);    // H0
    _Float16* P2    = (_Float16*)(w + 76800000);    // H1
    int*    srclist = (int*)(w + 102400000);        // 6.4 MB
    int*    off     = (int*)(w + 108800000);        // 400,016 B
    uint4*  Bp      = (uint4*)(w + 109300000);      // 98,304 B
    int*    gcur    = (int*)(w + 109450000);        // NBUCK ints

    // convert + pack + gcur zero (must precede scatter)
    convert_pack<<<CONV_BLKS + 24, 256, 0, stream>>>((const float4*)x, (uint4*)P0,
                                                     W0, W1, W2, Bp, gcur);
    // CSR build
    bucket_scatter<<<NB_SCAT, 256, 0, stream>>>(src, dst, gcur, pairs);
    bucket_fine<<<NBUCK, 256, 0, stream>>>(pairs, gcur, off, srclist);

    int grid = N_NODES / 16;   // 6250

    // layer 0: P0 -> P1
    gin_fused<<<grid, 256, 0, stream>>>((const uint4*)P0, Bp, b0, P1, off, srclist, 1);
    // layer 1: P1 -> P2
    gin_fused<<<grid, 256, 0, stream>>>((const uint4*)P1, Bp + 2048, b1, P2, off, srclist, 1);
    // layer 2: P2 -> P0
    gin_fused<<<grid, 256, 0, stream>>>((const uint4*)P2, Bp + 4096, b2, P0, off, srclist, 0);

    // pool + classifier
    pool_kernel<<<N_GRAPHS, 256, 0, stream>>>((const uint4*)P0, bat, Wg, bg, out);
}